// Round 9
// baseline (420.500 us; speedup 1.0000x reference)
//
#include <hip/hip_runtime.h>
#include <hip/hip_bf16.h>
#include <cstdint>
#include <cstddef>

// NaryTreeLSTM bottom-up:
//  - gemm_zx: preZ[node][4*256] = x @ [Wi|Wo|Wu|Wf]^T + bias for tail nodes (0..2046)
//    reads emb f32 directly (in-kernel cvt) — no separate convert pass.
//  - levels 15..11 (n>=2048): fused_level3 — LDS-staged MFMA kernel, BK=64,
//    XOR-swizzled sA/sB. emb (p==0) path reg-stages f32->bf16 (same layout);
//    hprev (p>=1) path uses global_load_lds.
//  - levels 10..0: ONE kernel, 64 blocks x 256 threads (16 d-tiles x 4 m-groups).
//    U-weights LDS-stationary per d-tile (XOR-swizzled). Levels 10..7 sync on a
//    hierarchical 8x8 grid barrier; levels 6..0 run on the 16 g==0 blocks only.
//
// Hard-won constraints:
//  * R2/R5: the job needs ~180 VGPRs. 1024-thread blocks (compiler caps VGPR
//    at 64) and min-occupancy launch bounds (cap 128) both cause scratch
//    spills (WRITE_SIZE 3MB->40-53MB, 2-3x slower). 256-thread blocks, plain
//    __launch_bounds__(256) ONLY.
//  * R3/R4: grid-barrier cost scales with population (~40ns/block flat);
//    hierarchical arrival + population shrink are the proven fixes.
//  * R3: XOR swizzle (both-sides) kills LDS bank conflicts.
//  * R7: zero-LDS fused levels failed — B must be LDS-reused.
//  * R8: BK=64 + swizzle pushed all fused dispatches below the tail.
//
// Wpack[12][256][256] bf16: mats {Wi,Wo,Wu,Wf, Ui0,Uo0,Uu0,Uf0, Ui1,Uo1,Uu1,Uf1}
// biasv[4][256] fp32. h stored bf16, c fp32.
// f gates: f_l = sig(Wf x + bF + Uf0 h_l), f_r = sig(Wf x + bF + Uf1 h_r).

typedef __attribute__((ext_vector_type(8))) __bf16 bf16x8;
typedef __attribute__((ext_vector_type(4))) float floatx4;

#define TB 64   // tail grid: 16 d-tiles x 4 m-groups

__device__ __forceinline__ float sigf(float x) { return 1.0f / (1.0f + __expf(-x)); }

__device__ __forceinline__ void load_lds16(const void* g, void* l) {
    __builtin_amdgcn_global_load_lds(
        (const __attribute__((address_space(1))) unsigned int*)g,
        (__attribute__((address_space(3))) unsigned int*)l, 16, 0, 0);
}

// Load 8 f32, convert to 8 bf16 (RNE, same as __float2bfloat16 pass did).
__device__ __forceinline__ bf16x8 cvt8(const float* p) {
    float4 v0 = *(const float4*)p;
    float4 v1 = *(const float4*)(p + 4);
    __hip_bfloat16 tmp[8];
    tmp[0] = __float2bfloat16(v0.x); tmp[1] = __float2bfloat16(v0.y);
    tmp[2] = __float2bfloat16(v0.z); tmp[3] = __float2bfloat16(v0.w);
    tmp[4] = __float2bfloat16(v1.x); tmp[5] = __float2bfloat16(v1.y);
    tmp[6] = __float2bfloat16(v1.z); tmp[7] = __float2bfloat16(v1.w);
    return *(const bf16x8*)tmp;
}

__global__ void pack_weights(const float* __restrict__ Wi, const float* __restrict__ bi, const float* __restrict__ Ui,
                             const float* __restrict__ Wo, const float* __restrict__ bo, const float* __restrict__ Uo,
                             const float* __restrict__ Wu, const float* __restrict__ bu, const float* __restrict__ Uu,
                             const float* __restrict__ Wf, const float* __restrict__ bf, const float* __restrict__ Uf,
                             __hip_bfloat16* __restrict__ Wpack, float* __restrict__ biasv)
{
    int m = blockIdx.x;   // 0..11
    int d = blockIdx.y;   // 0..255
    int k = threadIdx.x;  // 0..255
    const float* tbl[12] = {Wi, Wo, Wu, Wf,
                            Ui, Uo, Uu, Uf,
                            Ui + 65536, Uo + 65536, Uu + 65536, Uf + 65536};
    Wpack[((size_t)m * 256 + d) * 256 + k] = __float2bfloat16(tbl[m][d * 256 + k]);
    if (m < 4 && k == 0) {
        const float* bt[4] = {bi, bo, bu, bf};
        biasv[m * 256 + d] = bt[m][d];
    }
}

// preZ[m][s*256+d] = sum_k emb[m][k]*Wpack[s*256+d][k] + biasv[s*256+d], m<M
__global__ __launch_bounds__(256) void gemm_zx(
    const float* __restrict__ emb,
    const __hip_bfloat16* __restrict__ Wpack,
    const float* __restrict__ biasv,
    float* __restrict__ preZ,
    int M)
{
    __shared__ __hip_bfloat16 sA[64 * 32];
    __shared__ __hip_bfloat16 sB[64 * 32];
    const int t = threadIdx.x;
    const int s = blockIdx.x >> 2;          // mat 0..3
    const int d0 = (blockIdx.x & 3) * 64;   // col block within mat
    const int bm0 = blockIdx.y * 64;
    const int lane = t & 63, w = t >> 6, lrow = lane & 15, q = lane >> 4;

    floatx4 acc[4];
    #pragma unroll
    for (int mt = 0; mt < 4; ++mt) acc[mt] = (floatx4){0.f, 0.f, 0.f, 0.f};

    for (int kk = 0; kk < 8; ++kk) {
        const int k0 = kk * 32;
        {
            int r = t >> 2, kc = t & 3;
            // A: reg-staged f32->bf16 (emb read once, no convert pass).
            *(bf16x8*)&sA[t * 8] = cvt8(emb + (size_t)(bm0 + r) * 256 + k0 + kc * 8);
            load_lds16(Wpack + (size_t)(s * 256 + d0 + r) * 256 + k0 + kc * 8, &sB[t * 8]);
        }
        __syncthreads();
        bf16x8 af[4];
        #pragma unroll
        for (int mt = 0; mt < 4; ++mt)
            af[mt] = *(const bf16x8*)&sA[(mt * 16 + lrow) * 32 + q * 8];
        bf16x8 bfr = *(const bf16x8*)&sB[(w * 16 + lrow) * 32 + q * 8];
        #pragma unroll
        for (int mt = 0; mt < 4; ++mt)
            acc[mt] = __builtin_amdgcn_mfma_f32_16x16x32_bf16(af[mt], bfr, acc[mt], 0, 0, 0);
        __syncthreads();
    }

    const int d = d0 + w * 16 + lrow;
    const float bv = biasv[s * 256 + d];
    #pragma unroll
    for (int mt = 0; mt < 4; ++mt)
        #pragma unroll
        for (int rr = 0; rr < 4; ++rr) {
            int m = bm0 + mt * 16 + q * 4 + rr;
            if (m < M) preZ[(size_t)m * 1024 + s * 256 + d] = acc[mt][rr] + bv;
        }
}

// ---- big levels: staged MFMA kernel, BK=64, swizzled (R8/R9) -------------
// Block: 64 rows (bm0) x 64 cols (dchunk) per gate, 4 waves; wave w owns cols
// dchunk*64 + w*16. Per K-chunk of 64: stage A (8KB) + NS B-mats (NS*8KB)
// with source-side XOR (chunk ^ (row&7)), one barrier pair, NS*2*4 MFMAs/wave.
// p==0 (emb) A-path: reg-staged f32->bf16 with the SAME swizzled placement.
// Read swizzle: physical chunk = (ks*4+q) ^ (lrow&7) -> 2 lanes/bank (free).
template<int NS, int NP>
__global__ __launch_bounds__(256) void fused_level3(
    const float* __restrict__ embX,
    const __hip_bfloat16* __restrict__ hprev,
    const float* __restrict__ cprev,
    const __hip_bfloat16* __restrict__ Wpack,
    const float* __restrict__ biasv,
    __hip_bfloat16* __restrict__ hout,
    float* __restrict__ cout,
    int M)
{
    __shared__ __hip_bfloat16 sA[64 * 64];
    __shared__ __hip_bfloat16 sB[NS * 64 * 64];
    const int t = threadIdx.x;
    const int dchunk = blockIdx.x;
    const int bm0 = blockIdx.y * 64;
    const int lane = t & 63;
    const int w = t >> 6;
    const int lrow = lane & 15;
    const int q = lane >> 4;

    floatx4 accS[3][4];
    floatx4 accF[NP][4];
    #pragma unroll
    for (int s = 0; s < 3; ++s)
        #pragma unroll
        for (int mt = 0; mt < 4; ++mt) accS[s][mt] = (floatx4){0.f, 0.f, 0.f, 0.f};
    #pragma unroll
    for (int p = 0; p < NP; ++p)
        #pragma unroll
        for (int mt = 0; mt < 4; ++mt) accF[p][mt] = (floatx4){0.f, 0.f, 0.f, 0.f};

    #pragma unroll
    for (int p = 0; p < NP; ++p) {
        for (int kk = 0; kk < 4; ++kk) {
            const int k0 = kk * 64;
            // Stage A: 512 16B-chunks (rows of 8 chunks), source-swizzled.
            if (p == 0) {
                #pragma unroll
                for (int rep = 0; rep < 2; ++rep) {
                    int C = rep * 256 + t;
                    int r = C >> 3, c0 = C & 7;
                    *(bf16x8*)&sA[C * 8] =
                        cvt8(embX + (size_t)(bm0 + r) * 256 + k0 + (c0 ^ (r & 7)) * 8);
                }
            } else {
                #pragma unroll
                for (int rep = 0; rep < 2; ++rep) {
                    int C = rep * 256 + t;
                    int r = C >> 3, c0 = C & 7;
                    load_lds16(hprev + (size_t)(bm0 + r) * 512 + (p - 1) * 256
                                     + k0 + (c0 ^ (r & 7)) * 8,
                               &sA[C * 8]);
                }
            }
            // Stage B: NS*512 chunks, source-swizzled.
            #pragma unroll
            for (int rep = 0; rep < NS * 2; ++rep) {
                int C = rep * 256 + t;
                int s = C >> 9, r = (C >> 3) & 63, c0 = C & 7;
                load_lds16(Wpack + (size_t)((p * 4 + s) * 256 + dchunk * 64 + r) * 256
                                 + k0 + (c0 ^ (r & 7)) * 8,
                           &sB[C * 8]);
            }
            __syncthreads();

            bf16x8 af[2][4];
            #pragma unroll
            for (int ks = 0; ks < 2; ++ks)
                #pragma unroll
                for (int mt = 0; mt < 4; ++mt)
                    af[ks][mt] = *(const bf16x8*)&sA[(mt * 16 + lrow) * 64
                                                     + (((ks * 4 + q) ^ (lrow & 7)) * 8)];
            #pragma unroll
            for (int s = 0; s < NS; ++s) {
                #pragma unroll
                for (int ks = 0; ks < 2; ++ks) {
                    bf16x8 bfr = *(const bf16x8*)&sB[(s * 64 + w * 16 + lrow) * 64
                                                     + (((ks * 4 + q) ^ (lrow & 7)) * 8)];
                    if (s < 3) {
                        #pragma unroll
                        for (int mt = 0; mt < 4; ++mt)
                            accS[s][mt] = __builtin_amdgcn_mfma_f32_16x16x32_bf16(af[ks][mt], bfr, accS[s][mt], 0, 0, 0);
                    } else {
                        #pragma unroll
                        for (int mt = 0; mt < 4; ++mt)
                            accF[p][mt] = __builtin_amdgcn_mfma_f32_16x16x32_bf16(af[ks][mt], bfr, accF[p][mt], 0, 0, 0);
                    }
                }
            }
            __syncthreads();
        }
    }

    const int d = dchunk * 64 + w * 16 + lrow;
    const float bI = biasv[d];
    const float bO = biasv[256 + d];
    const float bU = biasv[512 + d];
    const float bF = (NS == 4) ? biasv[768 + d] : 0.0f;
    #pragma unroll
    for (int mt = 0; mt < 4; ++mt) {
        #pragma unroll
        for (int rr = 0; rr < 4; ++rr) {
            const int m = bm0 + mt * 16 + q * 4 + rr;
            if (m >= M) continue;
            float iv = sigf(accS[0][mt][rr] + bI);
            float ov = sigf(accS[1][mt][rr] + bO);
            float uv = tanhf(accS[2][mt][rr] + bU);
            float c;
            if (NS == 4) {
                float fx = accF[0][mt][rr];
                float fl = sigf(fx + accF[NP >= 2 ? 1 : 0][mt][rr] + bF);
                float fr = sigf(fx + accF[NP >= 3 ? 2 : 0][mt][rr] + bF);
                c = iv * uv + fl * cprev[(size_t)m * 512 + d]
                            + fr * cprev[(size_t)m * 512 + 256 + d];
            } else {
                c = iv * uv;
            }
            cout[(size_t)m * 256 + d] = c;
            hout[(size_t)m * 256 + d] = __float2bfloat16(ov * tanhf(c));
        }
    }
}

// ---- tail: levels 10..0, 64 blocks x 256 threads (R6 jobs, R9 barrier) ---
// dt = bid&15 (d-tile), g = bid>>4 (m-group 0..3); 16 wave-slots per d-tile
// in the big phase (slot = g*4+w, stride 16). Levels 6..0: only g==0 blocks
// survive (slot = w, stride 4; nmt<=4 so coverage exact).
// Big barrier: hierarchical 8 groups x 8 blocks (R4-proven pattern) —
// arrival chain 8+8 RMWs instead of 64.
// sB XOR-swizzle: 16B chunk c of row r lives at physical chunk (c ^ (r&7));
// involution on the global source at staging and on the read index.
__global__ __launch_bounds__(256) void tail_levels(
    __hip_bfloat16* __restrict__ hbuf, float* __restrict__ cbuf,
    const __hip_bfloat16* __restrict__ Wpack,
    const float* __restrict__ preZ,
    unsigned* __restrict__ bar, float* __restrict__ out)
{
    __shared__ __hip_bfloat16 sB[8 * 16 * 256];   // 64 KB: U mats for this d-tile
    const int bid = blockIdx.x;
    const int t = threadIdx.x;
    const int dt = bid & 15;     // d-tile
    const int g = bid >> 4;      // m-group 0..3
    const int w = t >> 6, lane = t & 63, lrow = lane & 15, q = lane >> 4;

    // Stage U mats 4..11, rows dt*16..+16, once (survives inter-level fences).
    for (int rnd = 0; rnd < 16; ++rnd) {
        int C = rnd * 256 + t;               // physical chunk 0..4095
        int q8k = C & 31, r = (C >> 5) & 15, m8 = C >> 9;
        load_lds16(Wpack + (size_t)((4 + m8) * 256 + dt * 16 + r) * 256 + (q8k ^ (r & 7)) * 8,
                   &sB[(size_t)C * 8]);
    }
    __syncthreads();

    const int d = dt * 16 + lrow;
    unsigned barnum = 0;   // big barrier generation
    unsigned snum = 0;     // small (16-count) barrier generation

    for (int l = 10; l >= 0; --l) {
        if (l <= 6 && g != 0) break;   // 48 blocks exit after the l=7 barrier

        const int n = 1 << l;
        const int start = n - 1;
        const int startc = 2 * n - 1;
        const __hip_bfloat16* hp = hbuf + (size_t)startc * 256;
        const float* cp = cbuf + (size_t)startc * 256;
        __hip_bfloat16* ho = hbuf + (size_t)start * 256;
        float* co = cbuf + (size_t)start * 256;
        const int nmt = (n + 15) >> 4;
        const int slot   = (l > 6) ? (g * 4 + w) : w;
        const int stride = (l > 6) ? 16 : 4;

        for (int mt = slot; mt < nmt; mt += stride) {
            const int m0 = mt * 16;
            // Preload A fragments (children h): 16 independent loads.
            bf16x8 af[2][8];
            #pragma unroll
            for (int p = 0; p < 2; ++p)
                #pragma unroll
                for (int kk = 0; kk < 8; ++kk)
                    af[p][kk] = *(const bf16x8*)(hp + (size_t)(m0 + lrow) * 512 + p * 256 + kk * 32 + q * 8);
            // Preload z (bias folded) and child c.
            float zi[4][4], clr[2][4];
            #pragma unroll
            for (int rr = 0; rr < 4; ++rr) {
                int m = m0 + q * 4 + rr;
                #pragma unroll
                for (int s = 0; s < 4; ++s)
                    zi[s][rr] = preZ[(size_t)(start + m) * 1024 + s * 256 + d];
                clr[0][rr] = cp[(size_t)m * 512 + d];
                clr[1][rr] = cp[(size_t)m * 512 + 256 + d];
            }

            floatx4 accS[3], accF1, accF2;
            #pragma unroll
            for (int s = 0; s < 3; ++s)
                accS[s] = (floatx4){zi[s][0], zi[s][1], zi[s][2], zi[s][3]};
            accF1 = (floatx4){0.f, 0.f, 0.f, 0.f};
            accF2 = (floatx4){0.f, 0.f, 0.f, 0.f};

            #pragma unroll
            for (int p = 0; p < 2; ++p)
                #pragma unroll
                for (int kk = 0; kk < 8; ++kk)
                    #pragma unroll
                    for (int s = 0; s < 4; ++s) {
                        bf16x8 bfr = *(const bf16x8*)&sB[((p * 4 + s) * 16 + lrow) * 256
                                                         + (((kk * 4 + q) ^ (lrow & 7)) * 8)];
                        if (s < 3)
                            accS[s] = __builtin_amdgcn_mfma_f32_16x16x32_bf16(af[p][kk], bfr, accS[s], 0, 0, 0);
                        else if (p == 0)
                            accF1 = __builtin_amdgcn_mfma_f32_16x16x32_bf16(af[p][kk], bfr, accF1, 0, 0, 0);
                        else
                            accF2 = __builtin_amdgcn_mfma_f32_16x16x32_bf16(af[p][kk], bfr, accF2, 0, 0, 0);
                    }

            #pragma unroll
            for (int rr = 0; rr < 4; ++rr) {
                int m = m0 + q * 4 + rr;
                if (m >= n) continue;
                float iv = sigf(accS[0][rr]);
                float ov = sigf(accS[1][rr]);
                float uv = tanhf(accS[2][rr]);
                float fx = zi[3][rr];
                float fl = sigf(fx + accF1[rr]);
                float fr = sigf(fx + accF2[rr]);
                float c = iv * uv + fl * clr[0][rr] + fr * clr[1][rr];
                float hv = ov * tanhf(c);
                if (l == 0) {
                    out[d] = hv;           // root h, fp32
                    out[256 + d] = c;      // root c
                } else {
                    co[(size_t)m * 256 + d] = c;
                    ho[(size_t)m * 256 + d] = __float2bfloat16(hv);
                }
            }
        }

        if (l > 0) {
            __syncthreads();
            if (l > 6) {
                // Hierarchical 8x8 barrier (levels 10..7): per-group lines
                // bar[grp*16] -> leader line bar[128] -> generation bar[144].
                ++barnum;
                if (t == 0) {
                    const int grp = bid & 7;
                    unsigned v = __hip_atomic_fetch_add(&bar[grp * 16], 1, __ATOMIC_ACQ_REL,
                                                        __HIP_MEMORY_SCOPE_AGENT) + 1;
                    bool released = false;
                    if (v == barnum * 8u) {                // last of the 8 in this group
                        unsigned gv = __hip_atomic_fetch_add(&bar[128], 1, __ATOMIC_ACQ_REL,
                                                             __HIP_MEMORY_SCOPE_AGENT) + 1;
                        if (gv == barnum * 8u) {           // last group leader
                            __hip_atomic_fetch_add(&bar[144], 1, __ATOMIC_RELEASE,
                                                   __HIP_MEMORY_SCOPE_AGENT);
                            released = true;
                        }
                    }
                    if (!released)
                        while (__hip_atomic_load(&bar[144], __ATOMIC_RELAXED,
                                                 __HIP_MEMORY_SCOPE_AGENT) < barnum)
                            __builtin_amdgcn_s_sleep(1);
                }
            } else {
                // Flat 16-count barrier (levels 6..1, survivors only).
                ++snum;
                if (t == 0) {
                    unsigned v = __hip_atomic_fetch_add(&bar[160], 1, __ATOMIC_ACQ_REL,
                                                        __HIP_MEMORY_SCOPE_AGENT) + 1;
                    if (v == snum * 16u) {
                        __hip_atomic_fetch_add(&bar[176], 1, __ATOMIC_RELEASE,
                                               __HIP_MEMORY_SCOPE_AGENT);
                    } else {
                        while (__hip_atomic_load(&bar[176], __ATOMIC_RELAXED,
                                                 __HIP_MEMORY_SCOPE_AGENT) < snum)
                            __builtin_amdgcn_s_sleep(1);
                    }
                }
            }
            __syncthreads();
            __builtin_amdgcn_fence(__ATOMIC_ACQUIRE, "agent");
        }
    }
}

extern "C" void kernel_launch(void* const* d_in, const int* in_sizes, int n_in,
                              void* d_out, int out_size, void* d_ws, size_t ws_size,
                              hipStream_t stream)
{
    const float* emb = (const float*)d_in[0];
    const float* Wi  = (const float*)d_in[1];
    const float* bi  = (const float*)d_in[2];
    const float* Ui  = (const float*)d_in[3];
    const float* Wo  = (const float*)d_in[4];
    const float* bo  = (const float*)d_in[5];
    const float* Uo  = (const float*)d_in[6];
    const float* Wu  = (const float*)d_in[7];
    const float* bu  = (const float*)d_in[8];
    const float* Uu  = (const float*)d_in[9];
    const float* Wf  = (const float*)d_in[10];
    const float* bf  = (const float*)d_in[11];
    const float* Uf  = (const float*)d_in[12];

    char* p = (char*)d_ws;
    __hip_bfloat16* Wpack = (__hip_bfloat16*)p;  p += (size_t)12 * 256 * 256 * 2;
    float* biasv          = (float*)p;           p += (size_t)4 * 256 * 4;
    __hip_bfloat16* hbuf  = (__hip_bfloat16*)p;  p += (size_t)65535 * 256 * 2;
    float* cbuf           = (float*)p;           p += (size_t)65535 * 256 * 4;
    float* preZ           = (float*)p;           p += (size_t)2047 * 1024 * 4;
    unsigned* bar         = (unsigned*)p;        p += 1024;

    hipMemsetAsync(bar, 0, 1024, stream);
    pack_weights<<<dim3(12, 256), 256, 0, stream>>>(Wi, bi, Ui, Wo, bo, Uo, Wu, bu, Uu, Wf, bf, Uf,
                                                    Wpack, biasv);

    // x-phase pre-GEMM for tail nodes (levels 10..0 = nodes 0..2046).
    gemm_zx<<<dim3(16, 32), 256, 0, stream>>>(emb, Wpack, biasv, preZ, 2047);

    // Leaves: level 15, n = 32768. 1 phase, 3 slots, c = i*u.
    {
        const int n = 32768, start = n - 1;
        fused_level3<3, 1><<<dim3(4, n / 64), 256, 0, stream>>>(
            emb + (size_t)start * 256, nullptr, nullptr, Wpack, biasv,
            hbuf + (size_t)start * 256, cbuf + (size_t)start * 256, n);
    }
    // Big internal levels 14..11.
    for (int l = 14; l >= 11; --l) {
        const int n = 1 << l;
        const int start = n - 1;
        const int startc = 2 * n - 1;
        fused_level3<4, 3><<<dim3(4, n / 64), 256, 0, stream>>>(
            emb + (size_t)start * 256,
            hbuf + (size_t)startc * 256,
            cbuf + (size_t)startc * 256,
            Wpack, biasv,
            hbuf + (size_t)start * 256, cbuf + (size_t)start * 256, n);
    }

    // Tail: levels 10..0 in one kernel; writes root h,c to out directly.
    tail_levels<<<TB, 256, 0, stream>>>(hbuf, cbuf, Wpack, preZ, bar, (float*)d_out);
}

// Round 10
// 394.873 us; speedup vs baseline: 1.0649x; 1.0649x over previous
//
#include <hip/hip_runtime.h>
#include <hip/hip_bf16.h>
#include <cstdint>
#include <cstddef>

// NaryTreeLSTM bottom-up:
//  - gemm_zx: preZ[node][4*256] = x @ [Wi|Wo|Wu|Wf]^T + bias for tail nodes (0..2046)
//  - levels 15..11 (n>=2048): fused_level3 — LDS-staged MFMA kernel, BK=64,
//    XOR-swizzled sA/sB (conflict-free reads).
//  - levels 10..0: ONE kernel, 64 blocks x 256 threads (16 d-tiles x 4 m-groups).
//    U-weights LDS-stationary per d-tile (XOR-swizzled). Levels 10..8 sync on a
//    flat 64-count grid barrier; levels 7..0 run on the 16 g==0 blocks only
//    (R10: cut moved from l=6 to l=7 — saves one full-population barrier+fence
//    for +1 serial job-time; l7 nmt=8 covered 2 jobs/slot by 16 blocks).
//
// Hard-won constraints:
//  * R2/R5: the job needs ~180 VGPRs. 1024-thread blocks (compiler caps VGPR
//    at 64) and min-occupancy launch bounds (cap 128) both cause scratch
//    spills (WRITE_SIZE 3MB->40-53MB, 2-3x slower). 256-thread blocks, plain
//    __launch_bounds__(256) ONLY.
//  * R3/R4/R9: barrier cost = population term (~40ns/block) + LARGE fixed term
//    (agent-acquire fence => L2 invalidate on multi-XCD + release latency).
//    Hierarchical arrival only pays at 256 blocks (R9: worse at 64). Cut
//    barrier COUNT and POPULATION, keep flat arrival at <=64.
//  * R3: XOR swizzle (both-sides) kills LDS bank conflicts.
//  * R7: zero-LDS fused levels failed — B must be LDS-reused.
//  * R9: folding f32->bf16 cvt into A-staging serializes ahead of B's
//    global_load_lds and loses — keep the separate convert pass.
//
// Wpack[12][256][256] bf16: mats {Wi,Wo,Wu,Wf, Ui0,Uo0,Uu0,Uf0, Ui1,Uo1,Uu1,Uf1}
// biasv[4][256] fp32. h stored bf16, c fp32.
// f gates: f_l = sig(Wf x + bF + Uf0 h_l), f_r = sig(Wf x + bF + Uf1 h_r).

typedef __attribute__((ext_vector_type(8))) __bf16 bf16x8;
typedef __attribute__((ext_vector_type(4))) float floatx4;

#define TB 64   // tail grid: 16 d-tiles x 4 m-groups

__device__ __forceinline__ float sigf(float x) { return 1.0f / (1.0f + __expf(-x)); }

__device__ __forceinline__ void load_lds16(const void* g, void* l) {
    __builtin_amdgcn_global_load_lds(
        (const __attribute__((address_space(1))) unsigned int*)g,
        (__attribute__((address_space(3))) unsigned int*)l, 16, 0, 0);
}

__global__ void pack_weights(const float* __restrict__ Wi, const float* __restrict__ bi, const float* __restrict__ Ui,
                             const float* __restrict__ Wo, const float* __restrict__ bo, const float* __restrict__ Uo,
                             const float* __restrict__ Wu, const float* __restrict__ bu, const float* __restrict__ Uu,
                             const float* __restrict__ Wf, const float* __restrict__ bf, const float* __restrict__ Uf,
                             __hip_bfloat16* __restrict__ Wpack, float* __restrict__ biasv)
{
    int m = blockIdx.x;   // 0..11
    int d = blockIdx.y;   // 0..255
    int k = threadIdx.x;  // 0..255
    const float* tbl[12] = {Wi, Wo, Wu, Wf,
                            Ui, Uo, Uu, Uf,
                            Ui + 65536, Uo + 65536, Uu + 65536, Uf + 65536};
    Wpack[((size_t)m * 256 + d) * 256 + k] = __float2bfloat16(tbl[m][d * 256 + k]);
    if (m < 4 && k == 0) {
        const float* bt[4] = {bi, bo, bu, bf};
        biasv[m * 256 + d] = bt[m][d];
    }
}

__global__ void convert_f32_bf16(const float* __restrict__ in, __hip_bfloat16* __restrict__ out, int n4)
{
    int i = blockIdx.x * 256 + threadIdx.x;
    if (i >= n4) return;
    float4 v = ((const float4*)in)[i];
    __hip_bfloat16 tmp[4];
    tmp[0] = __float2bfloat16(v.x);
    tmp[1] = __float2bfloat16(v.y);
    tmp[2] = __float2bfloat16(v.z);
    tmp[3] = __float2bfloat16(v.w);
    *(ushort4*)(out + (size_t)i * 4) = *(const ushort4*)tmp;
}

// preZ[m][s*256+d] = sum_k embB[m][k]*Wpack[s*256+d][k] + biasv[s*256+d], m<M
__global__ __launch_bounds__(256) void gemm_zx(
    const __hip_bfloat16* __restrict__ embB,
    const __hip_bfloat16* __restrict__ Wpack,
    const float* __restrict__ biasv,
    float* __restrict__ preZ,
    int M)
{
    __shared__ __hip_bfloat16 sA[64 * 32];
    __shared__ __hip_bfloat16 sB[64 * 32];
    const int t = threadIdx.x;
    const int s = blockIdx.x >> 2;          // mat 0..3
    const int d0 = (blockIdx.x & 3) * 64;   // col block within mat
    const int bm0 = blockIdx.y * 64;
    const int lane = t & 63, w = t >> 6, lrow = lane & 15, q = lane >> 4;

    floatx4 acc[4];
    #pragma unroll
    for (int mt = 0; mt < 4; ++mt) acc[mt] = (floatx4){0.f, 0.f, 0.f, 0.f};

    for (int kk = 0; kk < 8; ++kk) {
        const int k0 = kk * 32;
        {
            int r = t >> 2, kc = t & 3;
            load_lds16(embB + (size_t)(bm0 + r) * 256 + k0 + kc * 8, &sA[t * 8]);
            load_lds16(Wpack + (size_t)(s * 256 + d0 + r) * 256 + k0 + kc * 8, &sB[t * 8]);
        }
        __syncthreads();
        bf16x8 af[4];
        #pragma unroll
        for (int mt = 0; mt < 4; ++mt)
            af[mt] = *(const bf16x8*)&sA[(mt * 16 + lrow) * 32 + q * 8];
        bf16x8 bfr = *(const bf16x8*)&sB[(w * 16 + lrow) * 32 + q * 8];
        #pragma unroll
        for (int mt = 0; mt < 4; ++mt)
            acc[mt] = __builtin_amdgcn_mfma_f32_16x16x32_bf16(af[mt], bfr, acc[mt], 0, 0, 0);
        __syncthreads();
    }

    const int d = d0 + w * 16 + lrow;
    const float bv = biasv[s * 256 + d];
    #pragma unroll
    for (int mt = 0; mt < 4; ++mt)
        #pragma unroll
        for (int rr = 0; rr < 4; ++rr) {
            int m = bm0 + mt * 16 + q * 4 + rr;
            if (m < M) preZ[(size_t)m * 1024 + s * 256 + d] = acc[mt][rr] + bv;
        }
}

// ---- big levels: staged MFMA kernel, BK=64, swizzled (R8) ----------------
// Block: 64 rows (bm0) x 64 cols (dchunk) per gate, 4 waves; wave w owns cols
// dchunk*64 + w*16. Per K-chunk of 64: stage A (8KB) + NS B-mats (NS*8KB)
// with source-side XOR (chunk ^ (row&7)), one barrier pair, NS*2*4 MFMAs/wave.
// Read swizzle: physical chunk = (ks*4+q) ^ (lrow&7) -> 2 lanes/bank (free).
template<int NS, int NP>
__global__ __launch_bounds__(256) void fused_level3(
    const __hip_bfloat16* __restrict__ embX,
    const __hip_bfloat16* __restrict__ hprev,
    const float* __restrict__ cprev,
    const __hip_bfloat16* __restrict__ Wpack,
    const float* __restrict__ biasv,
    __hip_bfloat16* __restrict__ hout,
    float* __restrict__ cout,
    int M)
{
    __shared__ __hip_bfloat16 sA[64 * 64];
    __shared__ __hip_bfloat16 sB[NS * 64 * 64];
    const int t = threadIdx.x;
    const int dchunk = blockIdx.x;
    const int bm0 = blockIdx.y * 64;
    const int lane = t & 63;
    const int w = t >> 6;
    const int lrow = lane & 15;
    const int q = lane >> 4;

    floatx4 accS[3][4];
    floatx4 accF[NP][4];
    #pragma unroll
    for (int s = 0; s < 3; ++s)
        #pragma unroll
        for (int mt = 0; mt < 4; ++mt) accS[s][mt] = (floatx4){0.f, 0.f, 0.f, 0.f};
    #pragma unroll
    for (int p = 0; p < NP; ++p)
        #pragma unroll
        for (int mt = 0; mt < 4; ++mt) accF[p][mt] = (floatx4){0.f, 0.f, 0.f, 0.f};

    #pragma unroll
    for (int p = 0; p < NP; ++p) {
        const __hip_bfloat16* Abase = (p == 0) ? embX : hprev;
        const int astride = (p == 0) ? 256 : 512;
        const int aoff = (p == 0) ? 0 : (p - 1) * 256;
        for (int kk = 0; kk < 4; ++kk) {
            const int k0 = kk * 64;
            // Stage A: 512 16B-chunks (rows of 8 chunks), source-swizzled.
            #pragma unroll
            for (int rep = 0; rep < 2; ++rep) {
                int C = rep * 256 + t;
                int r = C >> 3, c0 = C & 7;
                load_lds16(Abase + (size_t)(bm0 + r) * astride + aoff + k0 + (c0 ^ (r & 7)) * 8,
                           &sA[C * 8]);
            }
            // Stage B: NS*512 chunks, source-swizzled.
            #pragma unroll
            for (int rep = 0; rep < NS * 2; ++rep) {
                int C = rep * 256 + t;
                int s = C >> 9, r = (C >> 3) & 63, c0 = C & 7;
                load_lds16(Wpack + (size_t)((p * 4 + s) * 256 + dchunk * 64 + r) * 256
                                 + k0 + (c0 ^ (r & 7)) * 8,
                           &sB[C * 8]);
            }
            __syncthreads();

            bf16x8 af[2][4];
            #pragma unroll
            for (int ks = 0; ks < 2; ++ks)
                #pragma unroll
                for (int mt = 0; mt < 4; ++mt)
                    af[ks][mt] = *(const bf16x8*)&sA[(mt * 16 + lrow) * 64
                                                     + (((ks * 4 + q) ^ (lrow & 7)) * 8)];
            #pragma unroll
            for (int s = 0; s < NS; ++s) {
                #pragma unroll
                for (int ks = 0; ks < 2; ++ks) {
                    bf16x8 bfr = *(const bf16x8*)&sB[(s * 64 + w * 16 + lrow) * 64
                                                     + (((ks * 4 + q) ^ (lrow & 7)) * 8)];
                    if (s < 3) {
                        #pragma unroll
                        for (int mt = 0; mt < 4; ++mt)
                            accS[s][mt] = __builtin_amdgcn_mfma_f32_16x16x32_bf16(af[ks][mt], bfr, accS[s][mt], 0, 0, 0);
                    } else {
                        #pragma unroll
                        for (int mt = 0; mt < 4; ++mt)
                            accF[p][mt] = __builtin_amdgcn_mfma_f32_16x16x32_bf16(af[ks][mt], bfr, accF[p][mt], 0, 0, 0);
                    }
                }
            }
            __syncthreads();
        }
    }

    const int d = dchunk * 64 + w * 16 + lrow;
    const float bI = biasv[d];
    const float bO = biasv[256 + d];
    const float bU = biasv[512 + d];
    const float bF = (NS == 4) ? biasv[768 + d] : 0.0f;
    #pragma unroll
    for (int mt = 0; mt < 4; ++mt) {
        #pragma unroll
        for (int rr = 0; rr < 4; ++rr) {
            const int m = bm0 + mt * 16 + q * 4 + rr;
            if (m >= M) continue;
            float iv = sigf(accS[0][mt][rr] + bI);
            float ov = sigf(accS[1][mt][rr] + bO);
            float uv = tanhf(accS[2][mt][rr] + bU);
            float c;
            if (NS == 4) {
                float fx = accF[0][mt][rr];
                float fl = sigf(fx + accF[NP >= 2 ? 1 : 0][mt][rr] + bF);
                float fr = sigf(fx + accF[NP >= 3 ? 2 : 0][mt][rr] + bF);
                c = iv * uv + fl * cprev[(size_t)m * 512 + d]
                            + fr * cprev[(size_t)m * 512 + 256 + d];
            } else {
                c = iv * uv;
            }
            cout[(size_t)m * 256 + d] = c;
            hout[(size_t)m * 256 + d] = __float2bfloat16(ov * tanhf(c));
        }
    }
}

// ---- tail: levels 10..0, 64 blocks x 256 threads (R6 jobs, R10 cut@7) ----
// dt = bid&15 (d-tile), g = bid>>4 (m-group 0..3); 16 wave-slots per d-tile
// in the big phase (slot = g*4+w, stride 16). Levels 7..0: only g==0 blocks
// survive (slot = w, stride 4; l7 nmt=8 -> 2 jobs/slot, coverage exact).
// Barriers: flat 64-count after l10,l9,l8; flat 16-count after l7..l1.
// sB XOR-swizzle: 16B chunk c of row r lives at physical chunk (c ^ (r&7));
// involution on the global source at staging and on the read index.
__global__ __launch_bounds__(256) void tail_levels(
    __hip_bfloat16* __restrict__ hbuf, float* __restrict__ cbuf,
    const __hip_bfloat16* __restrict__ Wpack,
    const float* __restrict__ preZ,
    unsigned* __restrict__ bar, float* __restrict__ out)
{
    __shared__ __hip_bfloat16 sB[8 * 16 * 256];   // 64 KB: U mats for this d-tile
    const int bid = blockIdx.x;
    const int t = threadIdx.x;
    const int dt = bid & 15;     // d-tile
    const int g = bid >> 4;      // m-group 0..3
    const int w = t >> 6, lane = t & 63, lrow = lane & 15, q = lane >> 4;

    // Stage U mats 4..11, rows dt*16..+16, once (survives inter-level fences).
    for (int rnd = 0; rnd < 16; ++rnd) {
        int C = rnd * 256 + t;               // physical chunk 0..4095
        int q8k = C & 31, r = (C >> 5) & 15, m8 = C >> 9;
        load_lds16(Wpack + (size_t)((4 + m8) * 256 + dt * 16 + r) * 256 + (q8k ^ (r & 7)) * 8,
                   &sB[(size_t)C * 8]);
    }
    __syncthreads();

    const int d = dt * 16 + lrow;
    unsigned barnum = 0;   // big (64-count) barrier generation
    unsigned snum = 0;     // small (16-count) barrier generation

    for (int l = 10; l >= 0; --l) {
        if (l <= 7 && g != 0) break;   // 48 blocks exit after the l=8 barrier

        const int n = 1 << l;
        const int start = n - 1;
        const int startc = 2 * n - 1;
        const __hip_bfloat16* hp = hbuf + (size_t)startc * 256;
        const float* cp = cbuf + (size_t)startc * 256;
        __hip_bfloat16* ho = hbuf + (size_t)start * 256;
        float* co = cbuf + (size_t)start * 256;
        const int nmt = (n + 15) >> 4;
        const int slot   = (l > 7) ? (g * 4 + w) : w;
        const int stride = (l > 7) ? 16 : 4;

        for (int mt = slot; mt < nmt; mt += stride) {
            const int m0 = mt * 16;
            // Preload A fragments (children h): 16 independent loads.
            bf16x8 af[2][8];
            #pragma unroll
            for (int p = 0; p < 2; ++p)
                #pragma unroll
                for (int kk = 0; kk < 8; ++kk)
                    af[p][kk] = *(const bf16x8*)(hp + (size_t)(m0 + lrow) * 512 + p * 256 + kk * 32 + q * 8);
            // Preload z (bias folded) and child c.
            float zi[4][4], clr[2][4];
            #pragma unroll
            for (int rr = 0; rr < 4; ++rr) {
                int m = m0 + q * 4 + rr;
                #pragma unroll
                for (int s = 0; s < 4; ++s)
                    zi[s][rr] = preZ[(size_t)(start + m) * 1024 + s * 256 + d];
                clr[0][rr] = cp[(size_t)m * 512 + d];
                clr[1][rr] = cp[(size_t)m * 512 + 256 + d];
            }

            floatx4 accS[3], accF1, accF2;
            #pragma unroll
            for (int s = 0; s < 3; ++s)
                accS[s] = (floatx4){zi[s][0], zi[s][1], zi[s][2], zi[s][3]};
            accF1 = (floatx4){0.f, 0.f, 0.f, 0.f};
            accF2 = (floatx4){0.f, 0.f, 0.f, 0.f};

            #pragma unroll
            for (int p = 0; p < 2; ++p)
                #pragma unroll
                for (int kk = 0; kk < 8; ++kk)
                    #pragma unroll
                    for (int s = 0; s < 4; ++s) {
                        bf16x8 bfr = *(const bf16x8*)&sB[((p * 4 + s) * 16 + lrow) * 256
                                                         + (((kk * 4 + q) ^ (lrow & 7)) * 8)];
                        if (s < 3)
                            accS[s] = __builtin_amdgcn_mfma_f32_16x16x32_bf16(af[p][kk], bfr, accS[s], 0, 0, 0);
                        else if (p == 0)
                            accF1 = __builtin_amdgcn_mfma_f32_16x16x32_bf16(af[p][kk], bfr, accF1, 0, 0, 0);
                        else
                            accF2 = __builtin_amdgcn_mfma_f32_16x16x32_bf16(af[p][kk], bfr, accF2, 0, 0, 0);
                    }

            #pragma unroll
            for (int rr = 0; rr < 4; ++rr) {
                int m = m0 + q * 4 + rr;
                if (m >= n) continue;
                float iv = sigf(accS[0][rr]);
                float ov = sigf(accS[1][rr]);
                float uv = tanhf(accS[2][rr]);
                float fx = zi[3][rr];
                float fl = sigf(fx + accF1[rr]);
                float fr = sigf(fx + accF2[rr]);
                float c = iv * uv + fl * clr[0][rr] + fr * clr[1][rr];
                float hv = ov * tanhf(c);
                if (l == 0) {
                    out[d] = hv;           // root h, fp32
                    out[256 + d] = c;      // root c
                } else {
                    co[(size_t)m * 256 + d] = c;
                    ho[(size_t)m * 256 + d] = __float2bfloat16(hv);
                }
            }
        }

        if (l > 0) {
            __syncthreads();
            if (l > 7) {
                // Flat 64-count barrier (levels 10..8).
                ++barnum;
                if (t == 0) {
                    unsigned v = __hip_atomic_fetch_add(&bar[0], 1, __ATOMIC_ACQ_REL,
                                                        __HIP_MEMORY_SCOPE_AGENT) + 1;
                    if (v == barnum * 64u) {
                        __hip_atomic_fetch_add(&bar[64], 1, __ATOMIC_RELEASE,
                                               __HIP_MEMORY_SCOPE_AGENT);
                    } else {
                        while (__hip_atomic_load(&bar[64], __ATOMIC_RELAXED,
                                                 __HIP_MEMORY_SCOPE_AGENT) < barnum)
                            __builtin_amdgcn_s_sleep(1);
                    }
                }
            } else {
                // Flat 16-count barrier (levels 7..1, survivors only).
                ++snum;
                if (t == 0) {
                    unsigned v = __hip_atomic_fetch_add(&bar[128], 1, __ATOMIC_ACQ_REL,
                                                        __HIP_MEMORY_SCOPE_AGENT) + 1;
                    if (v == snum * 16u) {
                        __hip_atomic_fetch_add(&bar[192], 1, __ATOMIC_RELEASE,
                                               __HIP_MEMORY_SCOPE_AGENT);
                    } else {
                        while (__hip_atomic_load(&bar[192], __ATOMIC_RELAXED,
                                                 __HIP_MEMORY_SCOPE_AGENT) < snum)
                            __builtin_amdgcn_s_sleep(1);
                    }
                }
            }
            __syncthreads();
            __builtin_amdgcn_fence(__ATOMIC_ACQUIRE, "agent");
        }
    }
}

extern "C" void kernel_launch(void* const* d_in, const int* in_sizes, int n_in,
                              void* d_out, int out_size, void* d_ws, size_t ws_size,
                              hipStream_t stream)
{
    const float* emb = (const float*)d_in[0];
    const float* Wi  = (const float*)d_in[1];
    const float* bi  = (const float*)d_in[2];
    const float* Ui  = (const float*)d_in[3];
    const float* Wo  = (const float*)d_in[4];
    const float* bo  = (const float*)d_in[5];
    const float* Uo  = (const float*)d_in[6];
    const float* Wu  = (const float*)d_in[7];
    const float* bu  = (const float*)d_in[8];
    const float* Uu  = (const float*)d_in[9];
    const float* Wf  = (const float*)d_in[10];
    const float* bf  = (const float*)d_in[11];
    const float* Uf  = (const float*)d_in[12];

    char* p = (char*)d_ws;
    __hip_bfloat16* Wpack = (__hip_bfloat16*)p;  p += (size_t)12 * 256 * 256 * 2;
    float* biasv          = (float*)p;           p += (size_t)4 * 256 * 4;
    __hip_bfloat16* embB  = (__hip_bfloat16*)p;  p += (size_t)65535 * 256 * 2;
    __hip_bfloat16* hbuf  = (__hip_bfloat16*)p;  p += (size_t)65535 * 256 * 2;
    float* cbuf           = (float*)p;           p += (size_t)65535 * 256 * 4;
    float* preZ           = (float*)p;           p += (size_t)2047 * 1024 * 4;
    unsigned* bar         = (unsigned*)p;        p += 1024;

    hipMemsetAsync(bar, 0, 1024, stream);
    pack_weights<<<dim3(12, 256), 256, 0, stream>>>(Wi, bi, Ui, Wo, bo, Uo, Wu, bu, Uu, Wf, bf, Uf,
                                                    Wpack, biasv);
    convert_f32_bf16<<<(65535 * 256 / 4 + 255) / 256, 256, 0, stream>>>(emb, embB, 65535 * 256 / 4);

    // x-phase pre-GEMM for tail nodes (levels 10..0 = nodes 0..2046).
    gemm_zx<<<dim3(16, 32), 256, 0, stream>>>(embB, Wpack, biasv, preZ, 2047);

    // Leaves: level 15, n = 32768. 1 phase, 3 slots, c = i*u.
    {
        const int n = 32768, start = n - 1;
        fused_level3<3, 1><<<dim3(4, n / 64), 256, 0, stream>>>(
            embB + (size_t)start * 256, nullptr, nullptr, Wpack, biasv,
            hbuf + (size_t)start * 256, cbuf + (size_t)start * 256, n);
    }
    // Big internal levels 14..11.
    for (int l = 14; l >= 11; --l) {
        const int n = 1 << l;
        const int start = n - 1;
        const int startc = 2 * n - 1;
        fused_level3<4, 3><<<dim3(4, n / 64), 256, 0, stream>>>(
            embB + (size_t)start * 256,
            hbuf + (size_t)startc * 256,
            cbuf + (size_t)startc * 256,
            Wpack, biasv,
            hbuf + (size_t)start * 256, cbuf + (size_t)start * 256, n);
    }

    // Tail: levels 10..0 in one kernel; writes root h,c to out directly.
    tail_levels<<<TB, 256, 0, stream>>>(hbuf, cbuf, Wpack, preZ, bar, (float*)d_out);
}